// Round 6
// baseline (135.890 us; speedup 1.0000x reference)
//
#include <hip/hip_runtime.h>

// SSIM (win=11, sigma=1.5, range=255), N=16 C=3 512x512 fp32 -> [16,502,502].
// R12: f16 cooperative reg-staging, ALL 3 channels in flight, 3 blocks/CU.
// R11 (f32 global_load_lds, 1-channel-deep double buffer) won 52.6->43.8us,
// proving staging is the lever. Residual analysis: per block-channel 4.4K
// cycles vs ~1.5K issue work; staging loaded-latency ~2.5K > per-channel
// compute ~1.5K, so a 1-deep pipeline exposes ~1K+/channel + full prologue.
// Memory-latency-pipeline-bound, not BW (25%), not conflicts (R9), not RAW
// (R10). Fix:
//  * Stage in f16 (halves s_in): cooperative reg-staging -- global dwordx4
//    -> scalar RNE (_Float16) casts (SAME conversion point as pack8 =>
//    bit-identical values) -> ds_write_b64. global_load_lds can't convert;
//    the VGPR round trip is paid ONCE per element cooperatively (32 cvts
//    per wave-channel vs 96 in the old per-wave pack path).
//  * All 24 loads (3ch x 2 inputs x 4 chunk-ops) issued back-to-back per
//    wave: 24KB in flight/wave vs R11's 16 peak / 8 steady. ONE exposed
//    load latency per block. ONE barrier; compute then runs 3 channels
//    with zero barriers / zero vmcnt waits (s_ht wave-private, per-wave
//    DS in-order, validated R3-R11).
//  * LDS 53.3KB = s_f16[3][2][48*80] 46080 + s_ht[64][56] 7168 + wtab 32
//    -> 3 blocks/CU (was 2), 12 waves/CU. launch_bounds(256,3).
//  * s_ht single buffer (R9 proved ping-pong ~= single).
// Channel order, qi independence, SSIM math unchanged -> absmax 0.0078125.
// Tripwire: WRITE_SIZE > 25MB = spill from the 24-float4 in-flight array.
//
// Edge clamps (uniform min(), no scalar fallback): staged data are always
// real (clamped-address) input values -- no garbage in LDS, so NaN x 0 is
// impossible. Clamped cols feed only zero band-weights (k-n>10) or outputs
// masked at the store (outcol>=502); clamped rows (r>=32 when row0=480)
// feed only outrows >=502, masked. Same proof as R6-R11.
//
// MFMA scheme (mfma_f32_16x16x32_f16), B[k][n] = W[k-n] banded, both passes:
//  H: A[m=row][k=col] -> D[m=row][n=outcol]; C-layout (col=lane&15,
//     row=(lane>>4)*4+reg) -> ds_write_b64 transposed into H_T[outcol][row].
//  V: A[m=outcol][k=row] from H_T (k contiguous -> ds_read_b128),
//     D[m=outcol][n=outrow]. Wave owns a 16-outcol chunk for both passes.

namespace {

constexpr int NN = 16, CC = 3, HH = 512, WW = 512;
constexpr int OH = HH - 10, OW = WW - 10;          // 502 x 502
constexpr int TW = 64, TH = 32;                    // output tile per block
constexpr int SR = 48, SC = 80;                    // staged tile rows x cols
constexpr int PIT = 80;                            // staged pitch (f16)
constexpr int HPITCH = 56;                         // H_T row pitch (f16)
constexpr float C1c = 6.5025f;                     // (0.01*255)^2
constexpr float C2c = 58.5225f;                    // (0.03*255)^2

typedef _Float16 half8   __attribute__((ext_vector_type(8)));
typedef _Float16 half4   __attribute__((ext_vector_type(4)));
typedef float    floatv4 __attribute__((ext_vector_type(4)));

__device__ const float WF[11] = {
    0.00102838f, 0.00759876f, 0.03600077f, 0.10936069f, 0.21300553f,
    0.26601172f,
    0.21300553f, 0.10936069f, 0.03600077f, 0.00759876f, 0.00102838f
};

__global__ __launch_bounds__(256, 3)
void ssim_kernel(const float* __restrict__ X, const float* __restrict__ Y,
                 float* __restrict__ out)
{
    // staged f16 input: [ch][x/y][48*80] = 46080 B
    __shared__ __align__(16) _Float16 s_f16[CC][2][SR * PIT];
    // transpose buffer (single; R9 proved ping-pong neutral): 7168 B
    __shared__ __align__(16) _Float16 s_ht[TW][HPITCH];
    __shared__ _Float16 s_wtab[16];

    const int tid  = threadIdx.x;
    const int lane = tid & 63;
    const int wv   = tid >> 6;          // wave id = outcol chunk (16 cols)
    const int col0 = blockIdx.x * TW;
    const int row0 = blockIdx.y * TH;
    const int n    = blockIdx.z;

    if (tid < 16) s_wtab[tid] = (tid < 11) ? (_Float16)WF[tid] : (_Float16)0.f;
    __syncthreads();

    // banded weight fragment B[k][n] = W[k-n]; lane: n=lane&15, k=(lane>>4)*8+j
    half8 bfrag;
    {
        const int bn = lane & 15, kq = (lane >> 4) * 8;
        #pragma unroll
        for (int j = 0; j < 8; ++j) {
            int kk = kq + j - bn;
            kk = (kk < 0 || kk > 10) ? 11 : kk;   // index 11 holds 0
            bfrag[j] = s_wtab[kk];
        }
    }

    const int arow = lane & 15;          // A m-row select / V outrow-local
    const int aq   = lane >> 4;          // A k-quad
    const int crow = aq * 4;             // C-layout row base

    // staging chunk map: 960 chunks (48 rows x 20 col-quads); wave w stages
    // chunks (w*4+i)*64+lane, i<4 (w<3) / i<3 (w==3) -- full-lane wave ops
    const int sCnt = (wv < 3) ? 4 : 3;
    int srcOff[4], ldsOff[4];
    #pragma unroll
    for (int i = 0; i < 4; ++i) {
        const int c  = (wv * 4 + i) * 64 + lane;
        const int r  = c / 20;
        const int c4 = c - r * 20;
        int gr = row0 + r;        gr = gr < HH ? gr : HH - 1;
        int gc = col0 + c4 * 4;   gc = gc <= WW - 4 ? gc : WW - 4;
        srcOff[i] = gr * WW + gc;          // f32 index
        ldsOff[i] = r * PIT + c4 * 4;      // f16 index
    }

    const size_t plane = (size_t)HH * WW;
    const float* Xn = X + (size_t)n * CC * plane;
    const float* Yn = Y + (size_t)n * CC * plane;

    // ---- issue ALL 24 global loads back-to-back (max MLP) ----
    float4 L[CC][2][4];
    #pragma unroll
    for (int ch = 0; ch < CC; ++ch) {
        #pragma unroll
        for (int i = 0; i < 4; ++i) {
            if (i < sCnt) {   // wave-uniform
                L[ch][0][i] = *(const float4*)(Xn + (size_t)ch * plane + srcOff[i]);
                L[ch][1][i] = *(const float4*)(Yn + (size_t)ch * plane + srcOff[i]);
            }
        }
    }

    // ---- drain: scalar RNE casts (bit-identical to pack8's conversion
    // point) -> ds_write_b64 ----
    #pragma unroll
    for (int ch = 0; ch < CC; ++ch) {
        #pragma unroll
        for (int s = 0; s < 2; ++s) {
            #pragma unroll
            for (int i = 0; i < 4; ++i) {
                if (i < sCnt) {
                    float4 v = L[ch][s][i];
                    half4 h = {(_Float16)v.x, (_Float16)v.y,
                               (_Float16)v.z, (_Float16)v.w};
                    *(half4*)&s_f16[ch][s][ldsOff[i]] = h;
                }
            }
        }
    }
    __syncthreads();   // staging complete; compute is barrier-free

    float acc[2][4] = {{0.f,0.f,0.f,0.f},{0.f,0.f,0.f,0.f}};
    const floatv4 zf = {0.f, 0.f, 0.f, 0.f};
    const int cbase = wv * 16 + aq * 8;   // fragment col base (f16 units)

    for (int ch = 0; ch < CC; ++ch) {
        // ---- fragment reads: 12x ds_read_b128, already f16 ----
        half8 axf[3], ayf[3];
        #pragma unroll
        for (int rc = 0; rc < 3; ++rc) {
            const int idx = (rc * 16 + arow) * PIT + cbase;
            axf[rc] = *(const half8*)&s_f16[ch][0][idx];
            ayf[rc] = *(const half8*)&s_f16[ch][1][idx];
        }

        // ---- H + V MFMA per quantity (s_ht wave-private; per-wave DS
        // in-order makes single-buffer reuse across q safe) ----
        floatv4 vfr[5][2];
        #pragma unroll
        for (int qi = 0; qi < 5; ++qi) {
            #pragma unroll
            for (int rc = 0; rc < 3; ++rc) {
                half8 a;
                if      (qi == 0) a = axf[rc] * ayf[rc];   // xy
                else if (qi == 1) a = axf[rc] * axf[rc];   // xx
                else if (qi == 2) a = axf[rc];             // x
                else if (qi == 3) a = ayf[rc] * ayf[rc];   // yy
                else              a = ayf[rc];             // y
                floatv4 d = __builtin_amdgcn_mfma_f32_16x16x32_f16(
                    a, bfrag, zf, 0, 0, 0);
                half4 h = {(_Float16)d[0], (_Float16)d[1],
                           (_Float16)d[2], (_Float16)d[3]};
                *(half4*)&s_ht[wv*16 + arow][rc*16 + crow] = h;
            }
            #pragma unroll
            for (int b = 0; b < 2; ++b) {
                half8 av = *(const half8*)&s_ht[wv*16 + arow][b*16 + aq*8];
                vfr[qi][b] = __builtin_amdgcn_mfma_f32_16x16x32_f16(
                    av, bfrag, zf, 0, 0, 0);
            }
        }

        // ---- SSIM on V fragments (vfr: 0=xy 1=xx 2=x 3=yy 4=y) ----
        #pragma unroll
        for (int b = 0; b < 2; ++b) {
            #pragma unroll
            for (int p = 0; p < 4; ++p) {
                float m1 = vfr[2][b][p], m2 = vfr[4][b][p];
                float exx = vfr[1][b][p], eyy = vfr[3][b][p],
                      exy = vfr[0][b][p];
                float m1s = m1*m1, m2s = m2*m2, m12 = m1*m2;
                float s1 = exx - m1s, s2 = eyy - m2s, s12 = exy - m12;
                float n1 = 2.f*m12 + C1c, d1 = m1s + m2s + C1c;
                float n2 = 2.f*s12 + C2c, d2 = s1 + s2 + C2c;
                acc[b][p] = fmaf(n1 * n2, __builtin_amdgcn_rcpf(d1 * d2),
                                 acc[b][p]);
            }
        }
    }

    // ---- epilogue: 1 - mean over channels ----
    #pragma unroll
    for (int b = 0; b < 2; ++b) {
        const int orow = row0 + b*16 + arow;
        const int ocol = col0 + wv*16 + crow;
        if (orow < OH) {
            float r0v = 1.f - acc[b][0] * (1.f/3.f);
            float r1v = 1.f - acc[b][1] * (1.f/3.f);
            float r2v = 1.f - acc[b][2] * (1.f/3.f);
            float r3v = 1.f - acc[b][3] * (1.f/3.f);
            size_t base = ((size_t)n * OH + orow) * OW + ocol;
            if (ocol + 3 < OW) {
                *(float2*)(out + base)     = make_float2(r0v, r1v);
                *(float2*)(out + base + 2) = make_float2(r2v, r3v);
            } else {
                float rs[4] = {r0v, r1v, r2v, r3v};
                #pragma unroll
                for (int p = 0; p < 4; ++p)
                    if (ocol + p < OW) out[base + p] = rs[p];
            }
        }
    }
}

} // namespace

extern "C" void kernel_launch(void* const* d_in, const int* in_sizes, int n_in,
                              void* d_out, int out_size, void* d_ws, size_t ws_size,
                              hipStream_t stream) {
    const float* X = (const float*)d_in[0];
    const float* Y = (const float*)d_in[1];
    float* out = (float*)d_out;

    dim3 grid((OW + TW - 1) / TW,   // 8
              (OH + TH - 1) / TH,   // 16
              NN);                  // 16
    ssim_kernel<<<grid, 256, 0, stream>>>(X, Y, out);
}

// Round 8
// 131.888 us; speedup vs baseline: 1.0303x; 1.0303x over previous
//
#include <hip/hip_runtime.h>

// SSIM (win=11, sigma=1.5, range=255), N=16 C=3 512x512 fp32 -> [16,502,502].
// R13 (resubmit; previous round's bench failed on infra, not the kernel):
// R11's winning dbuf-staging skeleton with f16 staged buffers -> 4
// blocks/CU (16 waves static, the VGPR-bin cap).
// Evidence: R11 (43.8us) == R12 (44.6us) despite different staging/MLP =>
// the wall is the compute phase; ~65% of cycles ALL resident waves stall on
// the per-wave chain (MFMA->cvt->ds_write->ds_read->MFMA per q). Waves/SIMD
// bins at VGPR 64/128/256: at VGPR 65..128 the cap is 16 waves/CU and LDS
// sets blocks/CU. R11 staged f32 (76.8KB -> 2 blocks); R12 staged 3ch f16
// (53.8KB -> 3). This round: f16 DOUBLE buffer s_in[2][2][48x80] = 30.7KB
// + s_ht 7.2KB = 37.9KB -> 4 blocks/CU. More resident chains = the only
// remaining occupancy lever; chain shortening is next if this nulls.
// Staging pipeline per channel (loads never in flight at a barrier, so
// __syncthreads' vmcnt(0) drain costs nothing):
//   LOAD(0); WRITE(0,buf0); bar; | LOAD(1); compute(0,buf0); WRITE(1,buf1);
//   bar; LOAD(2); compute(1,buf1); WRITE(2,buf0); bar; compute(2,buf0)
// LOAD(ch+1) flies under compute(ch) (~1.5K cyc >> L2/L3 latency). WAR on
// buf reuse (WRITE(2,buf0)) is protected by the barrier after WRITE(1):
// all waves passed compute(0) in program order. Compute core byte-identical
// to R9/R12 (proven); conversion point unchanged -> absmax stays 0.0078125.
//
// Edge clamps (uniform min(), no scalar fallback): staged data are always
// real (clamped-address) input values; clamped cols feed only zero
// band-weights (k-n>10) or store-masked outputs (outcol>=502); clamped rows
// feed only store-masked outrows. Same proof as R6-R12.
//
// MFMA scheme (mfma_f32_16x16x32_f16), B[k][n] = W[k-n] banded, both passes:
//  H: A[m=row][k=col] -> D[m=row][n=outcol]; C-layout (col=lane&15,
//     row=(lane>>4)*4+reg) -> ds_write_b64 transposed into H_T[outcol][row].
//  V: A[m=outcol][k=row] from H_T (k contiguous -> ds_read_b128),
//     D[m=outcol][n=outrow]. Wave owns a 16-outcol chunk for both passes.
// HPITCH=56 f16: both LDS patterns at structural bank minimum (R7-R12).

namespace {

constexpr int NN = 16, CC = 3, HH = 512, WW = 512;
constexpr int OH = HH - 10, OW = WW - 10;          // 502 x 502
constexpr int TW = 64, TH = 32;                    // output tile per block
constexpr int SR = 48;                             // staged tile rows
constexpr int PIT = 80;                            // staged pitch (f16)
constexpr int HPITCH = 56;                         // H_T row pitch (f16)
constexpr float C1c = 6.5025f;                     // (0.01*255)^2
constexpr float C2c = 58.5225f;                    // (0.03*255)^2

typedef _Float16 half8   __attribute__((ext_vector_type(8)));
typedef _Float16 half4   __attribute__((ext_vector_type(4)));
typedef float    floatv4 __attribute__((ext_vector_type(4)));

__device__ const float WF[11] = {
    0.00102838f, 0.00759876f, 0.03600077f, 0.10936069f, 0.21300553f,
    0.26601172f,
    0.21300553f, 0.10936069f, 0.03600077f, 0.00759876f, 0.00102838f
};

__global__ __launch_bounds__(256, 2)
void ssim_kernel(const float* __restrict__ X, const float* __restrict__ Y,
                 float* __restrict__ out)
{
    // f16 staged input, double-buffered: 2*2*48*80*2 = 30720 B
    __shared__ __align__(16) _Float16 s_in[2][2][SR * PIT];
    // transpose buffer (single; R9 proved ping-pong neutral): 7168 B
    __shared__ __align__(16) _Float16 s_ht[TW][HPITCH];
    __shared__ _Float16 s_wtab[16];

    const int tid  = threadIdx.x;
    const int lane = tid & 63;
    const int wv   = tid >> 6;          // wave id = outcol chunk (16 cols)
    const int col0 = blockIdx.x * TW;
    const int row0 = blockIdx.y * TH;
    const int n    = blockIdx.z;

    if (tid < 16) s_wtab[tid] = (tid < 11) ? (_Float16)WF[tid] : (_Float16)0.f;

    const int arow = lane & 15;          // A m-row select / V outrow-local
    const int aq   = lane >> 4;          // A k-quad
    const int crow = aq * 4;             // C-layout row base

    // staging chunk map: 960 chunks (48 rows x 20 col-quads); wave w stages
    // chunks (w*4+i)*64+lane, i<4 (w<3) / i<3 (w==3) -- full-lane wave ops
    const int sCnt = (wv < 3) ? 4 : 3;
    int srcOff[4], ldsOff[4];
    #pragma unroll
    for (int i = 0; i < 4; ++i) {
        const int c  = (wv * 4 + i) * 64 + lane;
        const int r  = c / 20;
        const int c4 = c - r * 20;
        int gr = row0 + r;        gr = gr < HH ? gr : HH - 1;
        int gc = col0 + c4 * 4;   gc = gc <= WW - 4 ? gc : WW - 4;
        srcOff[i] = gr * WW + gc;          // f32 index
        ldsOff[i] = r * PIT + c4 * 4;      // f16 index
    }

    const size_t plane = (size_t)HH * WW;
    const float* Xn = X + (size_t)n * CC * plane;
    const float* Yn = Y + (size_t)n * CC * plane;

    float4 L[2][4];   // in-flight channel (x/y), 32 VGPR

    auto LOAD = [&](int ch) {
        #pragma unroll
        for (int i = 0; i < 4; ++i) {
            if (i < sCnt) {   // wave-uniform
                L[0][i] = *(const float4*)(Xn + (size_t)ch * plane + srcOff[i]);
                L[1][i] = *(const float4*)(Yn + (size_t)ch * plane + srcOff[i]);
            }
        }
    };
    auto WRITE = [&](int b) {
        #pragma unroll
        for (int s = 0; s < 2; ++s) {
            #pragma unroll
            for (int i = 0; i < 4; ++i) {
                if (i < sCnt) {
                    float4 v = L[s][i];
                    half4 h = {(_Float16)v.x, (_Float16)v.y,
                               (_Float16)v.z, (_Float16)v.w};
                    *(half4*)&s_in[b][s][ldsOff[i]] = h;
                }
            }
        }
    };

    // ---- prologue: stage ch0 (one exposed load latency per block) ----
    LOAD(0);
    WRITE(0);
    __syncthreads();   // covers s_wtab too

    // banded weight fragment B[k][n] = W[k-n]; lane: n=lane&15, k=(lane>>4)*8+j
    half8 bfrag;
    {
        const int bn = lane & 15, kq = (lane >> 4) * 8;
        #pragma unroll
        for (int j = 0; j < 8; ++j) {
            int kk = kq + j - bn;
            kk = (kk < 0 || kk > 10) ? 11 : kk;   // index 11 holds 0
            bfrag[j] = s_wtab[kk];
        }
    }

    float acc[2][4] = {{0.f,0.f,0.f,0.f},{0.f,0.f,0.f,0.f}};
    const floatv4 zf = {0.f, 0.f, 0.f, 0.f};
    const int cbase = wv * 16 + aq * 8;   // fragment col base (f16 units)

    #pragma unroll
    for (int ch = 0; ch < CC; ++ch) {
        const int b = ch & 1;

        // issue next channel's loads: fly under this channel's compute
        if (ch + 1 < CC) LOAD(ch + 1);

        // ---- fragment reads: 12x ds_read_b128, already f16 ----
        half8 axf[3], ayf[3];
        #pragma unroll
        for (int rc = 0; rc < 3; ++rc) {
            const int idx = (rc * 16 + arow) * PIT + cbase;
            axf[rc] = *(const half8*)&s_in[b][0][idx];
            ayf[rc] = *(const half8*)&s_in[b][1][idx];
        }

        // ---- H + V MFMA per quantity (s_ht wave-private; per-wave DS
        // in-order makes single-buffer reuse across q safe) ----
        floatv4 vfr[5][2];
        #pragma unroll
        for (int qi = 0; qi < 5; ++qi) {
            #pragma unroll
            for (int rc = 0; rc < 3; ++rc) {
                half8 a;
                if      (qi == 0) a = axf[rc] * ayf[rc];   // xy
                else if (qi == 1) a = axf[rc] * axf[rc];   // xx
                else if (qi == 2) a = axf[rc];             // x
                else if (qi == 3) a = ayf[rc] * ayf[rc];   // yy
                else              a = ayf[rc];             // y
                floatv4 d = __builtin_amdgcn_mfma_f32_16x16x32_f16(
                    a, bfrag, zf, 0, 0, 0);
                half4 h = {(_Float16)d[0], (_Float16)d[1],
                           (_Float16)d[2], (_Float16)d[3]};
                *(half4*)&s_ht[wv*16 + arow][rc*16 + crow] = h;
            }
            #pragma unroll
            for (int bb = 0; bb < 2; ++bb) {
                half8 av = *(const half8*)&s_ht[wv*16 + arow][bb*16 + aq*8];
                vfr[qi][bb] = __builtin_amdgcn_mfma_f32_16x16x32_f16(
                    av, bfrag, zf, 0, 0, 0);
            }
        }

        // ---- SSIM on V fragments (vfr: 0=xy 1=xx 2=x 3=yy 4=y) ----
        #pragma unroll
        for (int bb = 0; bb < 2; ++bb) {
            #pragma unroll
            for (int p = 0; p < 4; ++p) {
                float m1 = vfr[2][bb][p], m2 = vfr[4][bb][p];
                float exx = vfr[1][bb][p], eyy = vfr[3][bb][p],
                      exy = vfr[0][bb][p];
                float m1s = m1*m1, m2s = m2*m2, m12 = m1*m2;
                float s1 = exx - m1s, s2 = eyy - m2s, s12 = exy - m12;
                float n1 = 2.f*m12 + C1c, d1 = m1s + m2s + C1c;
                float n2 = 2.f*s12 + C2c, d2 = s1 + s2 + C2c;
                acc[bb][p] = fmaf(n1 * n2, __builtin_amdgcn_rcpf(d1 * d2),
                                  acc[bb][p]);
            }
        }

        // ---- stage next channel into the other buffer, then sync ----
        if (ch + 1 < CC) {
            WRITE((ch + 1) & 1);   // WAR-safe: prior readers barrier-cleared
            __syncthreads();
        }
    }

    // ---- epilogue: 1 - mean over channels ----
    #pragma unroll
    for (int bb = 0; bb < 2; ++bb) {
        const int orow = row0 + bb*16 + arow;
        const int ocol = col0 + wv*16 + crow;
        if (orow < OH) {
            float r0v = 1.f - acc[bb][0] * (1.f/3.f);
            float r1v = 1.f - acc[bb][1] * (1.f/3.f);
            float r2v = 1.f - acc[bb][2] * (1.f/3.f);
            float r3v = 1.f - acc[bb][3] * (1.f/3.f);
            size_t base = ((size_t)n * OH + orow) * OW + ocol;
            if (ocol + 3 < OW) {
                *(float2*)(out + base)     = make_float2(r0v, r1v);
                *(float2*)(out + base + 2) = make_float2(r2v, r3v);
            } else {
                float rs[4] = {r0v, r1v, r2v, r3v};
                #pragma unroll
                for (int p = 0; p < 4; ++p)
                    if (ocol + p < OW) out[base + p] = rs[p];
            }
        }
    }
}

} // namespace

extern "C" void kernel_launch(void* const* d_in, const int* in_sizes, int n_in,
                              void* d_out, int out_size, void* d_ws, size_t ws_size,
                              hipStream_t stream) {
    const float* X = (const float*)d_in[0];
    const float* Y = (const float*)d_in[1];
    float* out = (float*)d_out;

    dim3 grid((OW + TW - 1) / TW,   // 8
              (OH + TH - 1) / TH,   // 16
              NN);                  // 16
    ssim_kernel<<<grid, 256, 0, stream>>>(X, Y, out);
}